// Round 1
// baseline (607.935 us; speedup 1.0000x reference)
//
#include <hip/hip_runtime.h>

#define NPTS 100000
#define P 64
#define C 128

typedef __bf16 bf16_t;
typedef __bf16 bf16x8 __attribute__((ext_vector_type(8)));
typedef float floatx4 __attribute__((ext_vector_type(4)));

// Workspace layout (bytes):
//   [0,      65536)  W1t bf16 [256][128]   (s1 folded, transposed: [n][k])
//   [65536, 131072)  W2t bf16 [128][256]   (s2 folded, transposed)
//   [131072,163840)  Wat bf16 [128][128]   (transposed)
//   [163840,294912)  acc  f32 [4][64*128]  (numOn, denOn, numOff, denOff)

__global__ __launch_bounds__(256) void prep_kernel(
    const float* __restrict__ W1, const float* __restrict__ s1,
    const float* __restrict__ W2, const float* __restrict__ s2,
    const float* __restrict__ Wa,
    bf16_t* __restrict__ W1t, bf16_t* __restrict__ W2t, bf16_t* __restrict__ Wat)
{
  int i0 = blockIdx.x * blockDim.x + threadIdx.x;
  int stride = gridDim.x * blockDim.x;
  for (int i = i0; i < 256 * 128; i += stride) {          // W1t[n][k] = W1[k][n]*s1[n]
    int n = i >> 7, k = i & 127;
    W1t[i] = (bf16_t)(W1[k * 256 + n] * s1[n]);
  }
  for (int i = i0; i < 128 * 256; i += stride) {          // W2t[n][k] = W2[k][n]*s2[n]
    int n = i >> 8, k = i & 255;
    W2t[i] = (bf16_t)(W2[k * 128 + n] * s2[n]);
  }
  for (int i = i0; i < 128 * 128; i += stride) {          // Wat[n][k] = Wa[k][n]
    int n = i >> 7, k = i & 127;
    Wat[i] = (bf16_t)(Wa[k * 128 + n]);
  }
}

// Fused per-point pipeline: feature -> h -> h2 -> (logit, a=h2@Wa) -> exp ->
// masked atomic pooling. One block = 64 points, 4 waves, MFMA 16x16x32 bf16.
__global__ __launch_bounds__(256) void main_kernel(
    const float* __restrict__ feature, const float* __restrict__ xyz,
    const float* __restrict__ ctr, const float* __restrict__ nrm,
    const float* __restrict__ pmn, const float* __restrict__ pmx,
    const float* __restrict__ b1, const float* __restrict__ b2,
    const float* __restrict__ W3, const float* __restrict__ b3,
    const bf16_t* __restrict__ W1t, const bf16_t* __restrict__ W2t,
    const bf16_t* __restrict__ Wat,
    float* __restrict__ accbuf, float* __restrict__ out_logit)
{
  // LDS: A1 bf16[64][136] (feature tile; later reused as h2 bf16)
  //      Hs bf16[64][264] (h; later overlaid by a f32[64][132])
  __shared__ __align__(16) char smem[17408 + 33792 + 2048 + 512];
  bf16_t* A1  = (bf16_t*)smem;
  bf16_t* Hs  = (bf16_t*)(smem + 17408);
  float*  aS  = (float*)(smem + 17408);
  float*  plS = (float*)(smem + 17408 + 33792);   // [64][8] nx,ny,nz,offs,minx,miny,maxx,maxy
  float*  w3S = (float*)(smem + 17408 + 33792 + 2048);

  const int tid  = threadIdx.x;
  const int wave = tid >> 6, lane = tid & 63;
  const int quad = lane >> 4, l16 = lane & 15;
  const int m0 = blockIdx.x * 64;

  // ---- stage plane params + W3 ----
  if (tid < 64) {
    int p = tid;
    float nx = nrm[p * 3 + 0], ny = nrm[p * 3 + 1], nz = nrm[p * 3 + 2];
    float cx = ctr[p * 3 + 0], cy = ctr[p * 3 + 1], cz = ctr[p * 3 + 2];
    plS[p * 8 + 0] = nx; plS[p * 8 + 1] = ny; plS[p * 8 + 2] = nz;
    plS[p * 8 + 3] = cx * nx + cy * ny + cz * nz;
    plS[p * 8 + 4] = pmn[p * 3 + 0]; plS[p * 8 + 5] = pmn[p * 3 + 1];
    plS[p * 8 + 6] = pmx[p * 3 + 0]; plS[p * 8 + 7] = pmx[p * 3 + 1];
  }
  if (tid < 128) w3S[tid] = W3[tid];

  // ---- stage feature tile (fp32 -> bf16) ----
  for (int i = tid; i < 64 * 32; i += 256) {   // 32 float4 per row
    int r = i >> 5, c4 = i & 31;
    float4 v = make_float4(0.f, 0.f, 0.f, 0.f);
    if (m0 + r < NPTS) v = *(const float4*)(feature + (size_t)(m0 + r) * C + c4 * 4);
    bf16_t* dst = A1 + r * 136 + c4 * 4;
    dst[0] = (bf16_t)v.x; dst[1] = (bf16_t)v.y; dst[2] = (bf16_t)v.z; dst[3] = (bf16_t)v.w;
  }
  __syncthreads();

  const floatx4 zero4 = {0.f, 0.f, 0.f, 0.f};

  // ---- GEMM1: h[64][256] = relu(A1 @ W1' + b1). Wave owns n-cols [wave*64, wave*64+64) ----
  {
    floatx4 acc[4][4];
#pragma unroll
    for (int mt = 0; mt < 4; ++mt)
#pragma unroll
      for (int nt = 0; nt < 4; ++nt) acc[mt][nt] = zero4;
#pragma unroll
    for (int kt = 0; kt < 4; ++kt) {
      bf16x8 af[4], bf[4];
#pragma unroll
      for (int mt = 0; mt < 4; ++mt)
        af[mt] = *(const bf16x8*)(A1 + (mt * 16 + l16) * 136 + kt * 32 + quad * 8);
#pragma unroll
      for (int nt = 0; nt < 4; ++nt)
        bf[nt] = *(const bf16x8*)(W1t + (wave * 64 + nt * 16 + l16) * 128 + kt * 32 + quad * 8);
#pragma unroll
      for (int mt = 0; mt < 4; ++mt)
#pragma unroll
        for (int nt = 0; nt < 4; ++nt)
          acc[mt][nt] = __builtin_amdgcn_mfma_f32_16x16x32_bf16(af[mt], bf[nt], acc[mt][nt], 0, 0, 0);
    }
#pragma unroll
    for (int nt = 0; nt < 4; ++nt) {
      int col = wave * 64 + nt * 16 + l16;
      float bias = b1[col];
#pragma unroll
      for (int mt = 0; mt < 4; ++mt)
#pragma unroll
        for (int r = 0; r < 4; ++r) {
          float hv = fmaxf(acc[mt][nt][r] + bias, 0.f);
          Hs[(mt * 16 + quad * 4 + r) * 264 + col] = (bf16_t)hv;
        }
    }
  }
  __syncthreads();

  // ---- GEMM2: h2[64][128] = relu(h @ W2' + b2) -> bf16 into A1 region ----
  {
    floatx4 acc[4][2];
#pragma unroll
    for (int mt = 0; mt < 4; ++mt) { acc[mt][0] = zero4; acc[mt][1] = zero4; }
#pragma unroll
    for (int kt = 0; kt < 8; ++kt) {
      bf16x8 af[4], bf[2];
#pragma unroll
      for (int mt = 0; mt < 4; ++mt)
        af[mt] = *(const bf16x8*)(Hs + (mt * 16 + l16) * 264 + kt * 32 + quad * 8);
#pragma unroll
      for (int nt = 0; nt < 2; ++nt)
        bf[nt] = *(const bf16x8*)(W2t + (wave * 32 + nt * 16 + l16) * 256 + kt * 32 + quad * 8);
#pragma unroll
      for (int mt = 0; mt < 4; ++mt)
#pragma unroll
        for (int nt = 0; nt < 2; ++nt)
          acc[mt][nt] = __builtin_amdgcn_mfma_f32_16x16x32_bf16(af[mt], bf[nt], acc[mt][nt], 0, 0, 0);
    }
#pragma unroll
    for (int nt = 0; nt < 2; ++nt) {
      int col = wave * 32 + nt * 16 + l16;
      float bias = b2[col];
#pragma unroll
      for (int mt = 0; mt < 4; ++mt)
#pragma unroll
        for (int r = 0; r < 4; ++r) {
          float hv = fmaxf(acc[mt][nt][r] + bias, 0.f);
          A1[(mt * 16 + quad * 4 + r) * 136 + col] = (bf16_t)hv;
        }
    }
  }
  __syncthreads();

  // ---- GEMMa: a[64][128] = h2 @ Wa -> f32 into aS (overlays Hs) ----
  {
    floatx4 acc[4][2];
#pragma unroll
    for (int mt = 0; mt < 4; ++mt) { acc[mt][0] = zero4; acc[mt][1] = zero4; }
#pragma unroll
    for (int kt = 0; kt < 4; ++kt) {
      bf16x8 af[4], bf[2];
#pragma unroll
      for (int mt = 0; mt < 4; ++mt)
        af[mt] = *(const bf16x8*)(A1 + (mt * 16 + l16) * 136 + kt * 32 + quad * 8);
#pragma unroll
      for (int nt = 0; nt < 2; ++nt)
        bf[nt] = *(const bf16x8*)(Wat + (wave * 32 + nt * 16 + l16) * 128 + kt * 32 + quad * 8);
#pragma unroll
      for (int mt = 0; mt < 4; ++mt)
#pragma unroll
        for (int nt = 0; nt < 2; ++nt)
          acc[mt][nt] = __builtin_amdgcn_mfma_f32_16x16x32_bf16(af[mt], bf[nt], acc[mt][nt], 0, 0, 0);
    }
    __syncthreads();   // all GEMM2 reads of Hs done before overlaying with aS
#pragma unroll
    for (int nt = 0; nt < 2; ++nt) {
      int col = wave * 32 + nt * 16 + l16;
#pragma unroll
      for (int mt = 0; mt < 4; ++mt)
#pragma unroll
        for (int r = 0; r < 4; ++r)
          aS[(mt * 16 + quad * 4 + r) * 132 + col] = acc[mt][nt][r];
    }
  }
  __syncthreads();

  // ---- per-point epilogue: logit, masks, exp, atomic pooling ----
  // 4 threads per point; thread handles 32 channels.
  const int m = tid >> 2, g = tid & 3, c0g = g * 32;
  const int mg = m0 + m;
  const bool active = mg < NPTS;

  float lsum = 0.f;
#pragma unroll 8
  for (int c = 0; c < 32; ++c)
    lsum += (float)A1[m * 136 + c0g + c] * w3S[c0g + c];
  lsum += __shfl_xor(lsum, 1);
  lsum += __shfl_xor(lsum, 2);
  float logit = lsum + b3[0];
  if (active && g == 0) out_logit[mg] = logit;

  const bool on = logit > 0.f;   // sigmoid(logit) > 0.5
  float x = 0.f, y = 0.f, z = 0.f;
  if (active) { x = xyz[mg * 3]; y = xyz[mg * 3 + 1]; z = xyz[mg * 3 + 2]; }

  float* numB = accbuf + (on ? 0 : 2) * 8192;
  float* denB = numB + 8192;

  for (int p = 0; p < P; ++p) {
    const float* pl = plS + p * 8;
    float proj = x * pl[0] + y * pl[1] + z * pl[2];
    bool hit = active && (fabsf(proj - pl[3]) < 0.1f) &&
               (x >= pl[4]) && (x < pl[6]) && (y >= pl[5]) && (y < pl[7]);
    if (hit) {
      // exp(a) without column-max: max subtraction cancels in num/den; a is O(±4).
#pragma unroll 8
      for (int c = 0; c < 32; ++c) {
        int cc = c0g + c;
        float e  = __expf(aS[m * 132 + cc]);
        float eh = e * (float)A1[m * 136 + cc];
        atomicAdd(numB + p * C + cc, eh);
        atomicAdd(denB + p * C + cc, e);
      }
    }
  }
}

// agg = num/(den+1e-9); out = relu(agg @ Wm + bm); concat ori. 128 blocks = 64 planes x {on,off}.
__global__ __launch_bounds__(128) void finalize_kernel(
    const float* __restrict__ accbuf, const float* __restrict__ Wm, const float* __restrict__ bm,
    const float* __restrict__ ctr, const float* __restrict__ nrm,
    const float* __restrict__ pmn, const float* __restrict__ pmx,
    float* __restrict__ out)
{
  int sel = blockIdx.x >> 6, p = blockIdx.x & 63;
  int j = threadIdx.x;
  __shared__ float aggS[128];
  const float* num = accbuf + sel * 16384 + p * C;
  const float* den = num + 8192;
  aggS[j] = num[j] / (den[j] + 1e-9f);
  __syncthreads();
  float s = bm[j];
#pragma unroll 4
  for (int c = 0; c < C; ++c) s += aggS[c] * Wm[c * C + j];
  s = fmaxf(s, 0.f);
  float* dst = out + NPTS + sel * (P * 140) + p * 140;
  dst[j] = s;
  if (j < 12) {
    float v;
    if (j < 3)      v = ctr[p * 3 + j];
    else if (j < 6) v = nrm[p * 3 + j - 3];
    else if (j < 9) v = pmn[p * 3 + j - 6];
    else            v = pmx[p * 3 + j - 9];
    dst[C + j] = v;
  }
}

extern "C" void kernel_launch(void* const* d_in, const int* in_sizes, int n_in,
                              void* d_out, int out_size, void* d_ws, size_t ws_size,
                              hipStream_t stream)
{
  const float* feature = (const float*)d_in[0];
  const float* xyz     = (const float*)d_in[1];
  const float* ctr     = (const float*)d_in[2];
  const float* nrm     = (const float*)d_in[3];
  const float* pmn     = (const float*)d_in[4];
  const float* pmx     = (const float*)d_in[5];
  const float* W1      = (const float*)d_in[6];
  const float* s1      = (const float*)d_in[7];
  const float* b1      = (const float*)d_in[8];
  const float* W2      = (const float*)d_in[9];
  const float* s2      = (const float*)d_in[10];
  const float* b2      = (const float*)d_in[11];
  const float* W3      = (const float*)d_in[12];
  const float* b3      = (const float*)d_in[13];
  const float* Wa      = (const float*)d_in[14];
  const float* Wm      = (const float*)d_in[15];
  const float* bm      = (const float*)d_in[16];
  float* out = (float*)d_out;

  char* ws = (char*)d_ws;
  bf16_t* W1t   = (bf16_t*)(ws);
  bf16_t* W2t   = (bf16_t*)(ws + 65536);
  bf16_t* Wat   = (bf16_t*)(ws + 131072);
  float*  accbuf = (float*)(ws + 163840);

  hipMemsetAsync(accbuf, 0, 4 * 8192 * sizeof(float), stream);
  prep_kernel<<<64, 256, 0, stream>>>(W1, s1, W2, s2, Wa, W1t, W2t, Wat);
  main_kernel<<<(NPTS + 63) / 64, 256, 0, stream>>>(
      feature, xyz, ctr, nrm, pmn, pmx, b1, b2, W3, b3, W1t, W2t, Wat, accbuf, out);
  finalize_kernel<<<128, 128, 0, stream>>>(accbuf, Wm, bm, ctr, nrm, pmn, pmx, out);
}

// Round 2
// 194.474 us; speedup vs baseline: 3.1261x; 3.1261x over previous
//
#include <hip/hip_runtime.h>

#define NPTS 100000
#define P 64
#define C 128
#define CHUNKS 16
#define CHUNK_PTS 6250      // 16 * 6250 = 100000
#define CHUNK_PAD 6400      // padded to multiple of 256

typedef __bf16 bf16_t;
typedef __bf16 bf16x8 __attribute__((ext_vector_type(8)));
typedef float floatx4 __attribute__((ext_vector_type(4)));

// Workspace layout (bytes):
//   [0,      65536)    W1t bf16 [256][128]   (s1 folded, transposed: [n][k])
//   [65536, 131072)    W2t bf16 [128][256]   (s2 folded, transposed)
//   [131072,163840)    Wat bf16 [128][128]   (transposed)
//   [163840, +51.2MB)  rec bf16 [NPTS][256]  (a[128] | h2[128] per point)
//   then               partial f32 [64][16][4][128]  (2 MB)

__global__ __launch_bounds__(256) void prep_kernel(
    const float* __restrict__ W1, const float* __restrict__ s1,
    const float* __restrict__ W2, const float* __restrict__ s2,
    const float* __restrict__ Wa,
    bf16_t* __restrict__ W1t, bf16_t* __restrict__ W2t, bf16_t* __restrict__ Wat)
{
  int i0 = blockIdx.x * blockDim.x + threadIdx.x;
  int stride = gridDim.x * blockDim.x;
  for (int i = i0; i < 256 * 128; i += stride) {          // W1t[n][k] = W1[k][n]*s1[n]
    int n = i >> 7, k = i & 127;
    W1t[i] = (bf16_t)(W1[k * 256 + n] * s1[n]);
  }
  for (int i = i0; i < 128 * 256; i += stride) {          // W2t[n][k] = W2[k][n]*s2[n]
    int n = i >> 8, k = i & 255;
    W2t[i] = (bf16_t)(W2[k * 128 + n] * s2[n]);
  }
  for (int i = i0; i < 128 * 128; i += stride) {          // Wat[n][k] = Wa[k][n]
    int n = i >> 7, k = i & 127;
    Wat[i] = (bf16_t)(Wa[k * 128 + n]);
  }
}

// Phase A: feature -> h -> h2 -> (logit, a=h2@Wa). Writes logit to out and
// per-point record {a bf16[128], h2 bf16[128]} to ws. NO global atomics.
__global__ __launch_bounds__(256) void main_kernel(
    const float* __restrict__ feature,
    const float* __restrict__ b1, const float* __restrict__ b2,
    const float* __restrict__ W3, const float* __restrict__ b3,
    const bf16_t* __restrict__ W1t, const bf16_t* __restrict__ W2t,
    const bf16_t* __restrict__ Wat,
    bf16_t* __restrict__ rec, float* __restrict__ out_logit)
{
  // LDS: A1 bf16[64][136] (feature tile; later h2)
  //      Hs bf16[64][264] (h; later overlaid by aB bf16[64][136])
  __shared__ __align__(16) char smem[17408 + 33792 + 512];
  bf16_t* A1  = (bf16_t*)smem;
  bf16_t* Hs  = (bf16_t*)(smem + 17408);
  bf16_t* aB  = (bf16_t*)(smem + 17408);          // overlays Hs after GEMM2
  float*  w3S = (float*)(smem + 17408 + 33792);

  const int tid  = threadIdx.x;
  const int wave = tid >> 6, lane = tid & 63;
  const int quad = lane >> 4, l16 = lane & 15;
  const int m0 = blockIdx.x * 64;

  if (tid < 128) w3S[tid] = W3[tid];

  // ---- stage feature tile (fp32 -> bf16) ----
  for (int i = tid; i < 64 * 32; i += 256) {   // 32 float4 per row
    int r = i >> 5, c4 = i & 31;
    float4 v = make_float4(0.f, 0.f, 0.f, 0.f);
    if (m0 + r < NPTS) v = *(const float4*)(feature + (size_t)(m0 + r) * C + c4 * 4);
    bf16_t* dst = A1 + r * 136 + c4 * 4;
    dst[0] = (bf16_t)v.x; dst[1] = (bf16_t)v.y; dst[2] = (bf16_t)v.z; dst[3] = (bf16_t)v.w;
  }
  __syncthreads();

  const floatx4 zero4 = {0.f, 0.f, 0.f, 0.f};

  // ---- GEMM1: h[64][256] = relu(A1 @ W1' + b1). Wave owns n-cols [wave*64,+64) ----
  {
    floatx4 acc[4][4];
#pragma unroll
    for (int mt = 0; mt < 4; ++mt)
#pragma unroll
      for (int nt = 0; nt < 4; ++nt) acc[mt][nt] = zero4;
#pragma unroll
    for (int kt = 0; kt < 4; ++kt) {
      bf16x8 af[4], bf[4];
#pragma unroll
      for (int mt = 0; mt < 4; ++mt)
        af[mt] = *(const bf16x8*)(A1 + (mt * 16 + l16) * 136 + kt * 32 + quad * 8);
#pragma unroll
      for (int nt = 0; nt < 4; ++nt)
        bf[nt] = *(const bf16x8*)(W1t + (wave * 64 + nt * 16 + l16) * 128 + kt * 32 + quad * 8);
#pragma unroll
      for (int mt = 0; mt < 4; ++mt)
#pragma unroll
        for (int nt = 0; nt < 4; ++nt)
          acc[mt][nt] = __builtin_amdgcn_mfma_f32_16x16x32_bf16(af[mt], bf[nt], acc[mt][nt], 0, 0, 0);
    }
#pragma unroll
    for (int nt = 0; nt < 4; ++nt) {
      int col = wave * 64 + nt * 16 + l16;
      float bias = b1[col];
#pragma unroll
      for (int mt = 0; mt < 4; ++mt)
#pragma unroll
        for (int r = 0; r < 4; ++r) {
          float hv = fmaxf(acc[mt][nt][r] + bias, 0.f);
          Hs[(mt * 16 + quad * 4 + r) * 264 + col] = (bf16_t)hv;
        }
    }
  }
  __syncthreads();

  // ---- GEMM2: h2[64][128] = relu(h @ W2' + b2) -> bf16 into A1 region ----
  {
    floatx4 acc[4][2];
#pragma unroll
    for (int mt = 0; mt < 4; ++mt) { acc[mt][0] = zero4; acc[mt][1] = zero4; }
#pragma unroll
    for (int kt = 0; kt < 8; ++kt) {
      bf16x8 af[4], bf[2];
#pragma unroll
      for (int mt = 0; mt < 4; ++mt)
        af[mt] = *(const bf16x8*)(Hs + (mt * 16 + l16) * 264 + kt * 32 + quad * 8);
#pragma unroll
      for (int nt = 0; nt < 2; ++nt)
        bf[nt] = *(const bf16x8*)(W2t + (wave * 32 + nt * 16 + l16) * 256 + kt * 32 + quad * 8);
#pragma unroll
      for (int mt = 0; mt < 4; ++mt)
#pragma unroll
        for (int nt = 0; nt < 2; ++nt)
          acc[mt][nt] = __builtin_amdgcn_mfma_f32_16x16x32_bf16(af[mt], bf[nt], acc[mt][nt], 0, 0, 0);
    }
#pragma unroll
    for (int nt = 0; nt < 2; ++nt) {
      int col = wave * 32 + nt * 16 + l16;
      float bias = b2[col];
#pragma unroll
      for (int mt = 0; mt < 4; ++mt)
#pragma unroll
        for (int r = 0; r < 4; ++r) {
          float hv = fmaxf(acc[mt][nt][r] + bias, 0.f);
          A1[(mt * 16 + quad * 4 + r) * 136 + col] = (bf16_t)hv;
        }
    }
  }
  __syncthreads();   // all GEMM2 Hs-reads done; A1 now h2

  // ---- GEMMa: a[64][128] = h2 @ Wa -> bf16 into aB (overlays Hs) ----
  {
    floatx4 acc[4][2];
#pragma unroll
    for (int mt = 0; mt < 4; ++mt) { acc[mt][0] = zero4; acc[mt][1] = zero4; }
#pragma unroll
    for (int kt = 0; kt < 4; ++kt) {
      bf16x8 af[4], bf[2];
#pragma unroll
      for (int mt = 0; mt < 4; ++mt)
        af[mt] = *(const bf16x8*)(A1 + (mt * 16 + l16) * 136 + kt * 32 + quad * 8);
#pragma unroll
      for (int nt = 0; nt < 2; ++nt)
        bf[nt] = *(const bf16x8*)(Wat + (wave * 32 + nt * 16 + l16) * 128 + kt * 32 + quad * 8);
#pragma unroll
      for (int mt = 0; mt < 4; ++mt)
#pragma unroll
        for (int nt = 0; nt < 2; ++nt)
          acc[mt][nt] = __builtin_amdgcn_mfma_f32_16x16x32_bf16(af[mt], bf[nt], acc[mt][nt], 0, 0, 0);
    }
#pragma unroll
    for (int nt = 0; nt < 2; ++nt) {
      int col = wave * 32 + nt * 16 + l16;
#pragma unroll
      for (int mt = 0; mt < 4; ++mt)
#pragma unroll
        for (int r = 0; r < 4; ++r)
          aB[(mt * 16 + quad * 4 + r) * 136 + col] = (bf16_t)acc[mt][nt][r];
    }
  }
  __syncthreads();

  // ---- logit: 4 threads/point, 32 channels each ----
  {
    const int m = tid >> 2, g = tid & 3, c0g = g * 32;
    const int mg = m0 + m;
    float lsum = 0.f;
#pragma unroll 8
    for (int c = 0; c < 32; ++c)
      lsum += (float)A1[m * 136 + c0g + c] * w3S[c0g + c];
    lsum += __shfl_xor(lsum, 1);
    lsum += __shfl_xor(lsum, 2);
    if (mg < NPTS && g == 0) out_logit[mg] = lsum + b3[0];
  }

  // ---- record write: rec[pt] = {a[0:128], h2[0:128]} bf16, coalesced 8B/lane ----
  for (int i = tid; i < 64 * 64; i += 256) {
    int pt = i >> 6, slot = i & 63;
    if (m0 + pt < NPTS) {
      const bf16_t* src = (slot < 32) ? (aB + pt * 136 + slot * 4)
                                      : (A1 + pt * 136 + (slot - 32) * 4);
      uint2 v = *(const uint2*)src;
      *(uint2*)(rec + (size_t)(m0 + pt) * 256 + slot * 4) = v;
    }
  }
}

// Phase B: 64 planes x 16 chunks. Scan xyz, ballot hits, wave-cooperative
// record load + register accumulation (lane owns channels 2l, 2l+1).
__global__ __launch_bounds__(256) void pool_kernel(
    const float* __restrict__ xyz, const float* __restrict__ out_logit,
    const bf16_t* __restrict__ rec,
    const float* __restrict__ ctr, const float* __restrict__ nrm,
    const float* __restrict__ pmn, const float* __restrict__ pmx,
    float* __restrict__ partial)
{
  const int plane = blockIdx.x >> 4;
  const int chunk = blockIdx.x & 15;
  const int tid = threadIdx.x, lane = tid & 63;

  __shared__ float accS[4][128];   // num_on, den_on, num_off, den_off
  for (int i = tid; i < 512; i += 256) ((float*)accS)[i] = 0.f;

  const float nx = nrm[plane * 3], ny = nrm[plane * 3 + 1], nz = nrm[plane * 3 + 2];
  const float offs = ctr[plane * 3] * nx + ctr[plane * 3 + 1] * ny + ctr[plane * 3 + 2] * nz;
  const float mnx = pmn[plane * 3], mny = pmn[plane * 3 + 1];
  const float mxx = pmx[plane * 3], mxy = pmx[plane * 3 + 1];
  __syncthreads();

  const int base = chunk * CHUNK_PTS;
  float nOn0 = 0, nOn1 = 0, dOn0 = 0, dOn1 = 0;
  float nOf0 = 0, nOf1 = 0, dOf0 = 0, dOf1 = 0;

  for (int i = tid; i < CHUNK_PAD; i += 256) {
    int pt = base + i;
    bool hit = false;
    if (i < CHUNK_PTS) {
      float x = xyz[pt * 3], y = xyz[pt * 3 + 1], z = xyz[pt * 3 + 2];
      float proj = x * nx + y * ny + z * nz;
      hit = (fabsf(proj - offs) < 0.1f) &&
            (x >= mnx) && (x < mxx) && (y >= mny) && (y < mxy);
    }
    unsigned long long m = __ballot(hit);
    while (m) {
      int l = __builtin_ctzll(m);
      m &= m - 1;
      int hpt = __shfl(pt, l);
      float lg = out_logit[hpt];                       // broadcast load
      const unsigned* r32 = (const unsigned*)(rec + (size_t)hpt * 256);
      unsigned ap = r32[lane];
      unsigned hp = r32[64 + lane];
      float a0 = __uint_as_float(ap << 16);
      float a1 = __uint_as_float(ap & 0xffff0000u);
      float h0 = __uint_as_float(hp << 16);
      float h1 = __uint_as_float(hp & 0xffff0000u);
      float e0 = __expf(a0), e1 = __expf(a1);
      if (lg > 0.f) { nOn0 += e0 * h0; nOn1 += e1 * h1; dOn0 += e0; dOn1 += e1; }
      else          { nOf0 += e0 * h0; nOf1 += e1 * h1; dOf0 += e0; dOf1 += e1; }
    }
  }

  atomicAdd(&accS[0][lane * 2],     nOn0);
  atomicAdd(&accS[0][lane * 2 + 1], nOn1);
  atomicAdd(&accS[1][lane * 2],     dOn0);
  atomicAdd(&accS[1][lane * 2 + 1], dOn1);
  atomicAdd(&accS[2][lane * 2],     nOf0);
  atomicAdd(&accS[2][lane * 2 + 1], nOf1);
  atomicAdd(&accS[3][lane * 2],     dOf0);
  atomicAdd(&accS[3][lane * 2 + 1], dOf1);
  __syncthreads();

  float* dst = partial + (size_t)blockIdx.x * 512;
  for (int i = tid; i < 512; i += 256) dst[i] = ((float*)accS)[i];
}

// Finalize: sum partials over chunks, agg = num/(den+1e-9), relu(agg@Wm+bm), ori.
__global__ __launch_bounds__(128) void finalize_kernel(
    const float* __restrict__ partial,
    const float* __restrict__ Wm, const float* __restrict__ bm,
    const float* __restrict__ ctr, const float* __restrict__ nrm,
    const float* __restrict__ pmn, const float* __restrict__ pmx,
    float* __restrict__ out)
{
  int sel = blockIdx.x >> 6, p = blockIdx.x & 63;
  int j = threadIdx.x;
  float num = 0.f, den = 0.f;
  const float* bp = partial + (size_t)p * 16 * 512 + sel * 2 * 128;
#pragma unroll
  for (int k = 0; k < 16; ++k) {
    num += bp[k * 512 + j];
    den += bp[k * 512 + 128 + j];
  }
  __shared__ float aggS[128];
  aggS[j] = num / (den + 1e-9f);
  __syncthreads();
  float s = bm[j];
#pragma unroll 4
  for (int c = 0; c < C; ++c) s += aggS[c] * Wm[c * C + j];
  s = fmaxf(s, 0.f);
  float* dst = out + NPTS + sel * (P * 140) + p * 140;
  dst[j] = s;
  if (j < 12) {
    float v;
    if (j < 3)      v = ctr[p * 3 + j];
    else if (j < 6) v = nrm[p * 3 + j - 3];
    else if (j < 9) v = pmn[p * 3 + j - 6];
    else            v = pmx[p * 3 + j - 9];
    dst[C + j] = v;
  }
}

extern "C" void kernel_launch(void* const* d_in, const int* in_sizes, int n_in,
                              void* d_out, int out_size, void* d_ws, size_t ws_size,
                              hipStream_t stream)
{
  const float* feature = (const float*)d_in[0];
  const float* xyz     = (const float*)d_in[1];
  const float* ctr     = (const float*)d_in[2];
  const float* nrm     = (const float*)d_in[3];
  const float* pmn     = (const float*)d_in[4];
  const float* pmx     = (const float*)d_in[5];
  const float* W1      = (const float*)d_in[6];
  const float* s1      = (const float*)d_in[7];
  const float* b1      = (const float*)d_in[8];
  const float* W2      = (const float*)d_in[9];
  const float* s2      = (const float*)d_in[10];
  const float* b2      = (const float*)d_in[11];
  const float* W3      = (const float*)d_in[12];
  const float* b3      = (const float*)d_in[13];
  const float* Wa      = (const float*)d_in[14];
  const float* Wm      = (const float*)d_in[15];
  const float* bm      = (const float*)d_in[16];
  float* out = (float*)d_out;

  char* ws = (char*)d_ws;
  bf16_t* W1t = (bf16_t*)(ws);
  bf16_t* W2t = (bf16_t*)(ws + 65536);
  bf16_t* Wat = (bf16_t*)(ws + 131072);
  bf16_t* rec = (bf16_t*)(ws + 163840);                       // NPTS*512 B
  float* partial = (float*)(ws + 163840 + (size_t)NPTS * 512); // 1024*512 f32

  prep_kernel<<<64, 256, 0, stream>>>(W1, s1, W2, s2, Wa, W1t, W2t, Wat);
  main_kernel<<<(NPTS + 63) / 64, 256, 0, stream>>>(
      feature, b1, b2, W3, b3, W1t, W2t, Wat, rec, out);
  pool_kernel<<<64 * CHUNKS, 256, 0, stream>>>(
      xyz, out, rec, ctr, nrm, pmn, pmx, partial);
  finalize_kernel<<<128, 128, 0, stream>>>(partial, Wm, bm, ctr, nrm, pmn, pmx, out);
}